// Round 8
// baseline (485.312 us; speedup 1.0000x reference)
//
#include <hip/hip_runtime.h>
#include <hip/hip_fp16.h>
#include <hip/hip_cooperative_groups.h>

namespace cg = cooperative_groups;

typedef __attribute__((ext_vector_type(8))) _Float16 half8;
typedef __attribute__((ext_vector_type(4))) float f32x4;
typedef unsigned int u32;
typedef unsigned short u16;
typedef unsigned long long u64;

#define ELL_PAD 64
#define BKT 128          // nodes per dst-bucket
#define BKT_SH 7
#define EPB 2048         // edges per parta work-unit
#define NAMAX 512
#define RUNCAP 3072

// Single cooperative kernel: all phases grid-stride, separated by grid.sync().
// LDS is one 49.7 KB union re-aliased per phase (parta 12.3K, partb 48.5K,
// layer 4.3K). Numerics bit-identical to the r6 multi-kernel pipeline.

struct Par {
  const float* x; const float* Ws; const float* bs;
  const int* esrc; const int* edst;
  int* deg_out; int* deg_in;
  u16* ell; _Float16* Whi; _Float16* Wlo;
  _Float16* xh0; _Float16* xh1; float* outf;
  u32* part; u32* runTab;
  int N, E, L, NA, NB, tiles, packTotal, padU32;
};

__global__ __launch_bounds__(512) void fused_all(Par p) {
  __shared__ __align__(16) char smem[49680];
  cg::grid_group grid = cg::this_grid();
  const int tid = threadIdx.x;

  // ---------------- P0: zero deg_out + phantom xh rows + pack W ----------------
  {
    int gt = blockIdx.x * 512 + tid, gs = gridDim.x * 512;
    for (int i = gt; i < p.N; i += gs) p.deg_out[i] = 0;
    u32* xz0 = (u32*)(p.xh0 + (size_t)p.N * 128);
    u32* xz1 = (u32*)(p.xh1 + (size_t)p.N * 128);
    for (int j = gt; j < p.padU32; j += gs) { xz0[j] = 0; xz1[j] = 0; }
    // B-fragment pack: elem j of (layer,ntile,kstep,lane) =
    // W[k=kstep*32+(lane>>4)*8+j][n=ntile*16+(lane&15)]
    for (int i = gt; i < p.packTotal; i += gs) {
      int lane = i & 63, kstep = (i >> 6) & 3, ntile = (i >> 8) & 7, layer = i >> 11;
      int nn = ntile * 16 + (lane & 15);
      int k0 = kstep * 32 + (lane >> 4) * 8;
      const float* W = p.Ws + (size_t)layer * 128 * 128;
      size_t base = (size_t)i * 8;
      for (int j = 0; j < 8; j++) {
        float v = W[(k0 + j) * 128 + nn];
        _Float16 hi = (_Float16)v;
        p.Whi[base + j] = hi;
        p.Wlo[base + j] = (_Float16)(v - (float)hi);   // exact residual
      }
    }
  }
  grid.sync();

  // ---------------- P1: parta — counting sort of edges into dst-buckets --------
  {
    u32* hist  = (u32*)smem;            // 512 u32
    u32* stage = (u32*)(smem + 2048);   // 2048 u32 (8 KB)
    u32* scanA = (u32*)(smem + 10240);  // 512 u32
    for (int a = blockIdx.x; a < p.NA; a += gridDim.x) {
      __syncthreads();                  // protect stage/hist across iterations
      int e0 = a * EPB, e1 = min(p.E, e0 + EPB), len = e1 - e0;
      if (tid <= p.NB) hist[tid] = 0;
      __syncthreads();
      for (int i = e0 + tid; i < e1; i += 512) {
        int s = p.esrc[i], d = p.edst[i];
        atomicAdd(&p.deg_out[s], 1);
        atomicAdd(&hist[d >> BKT_SH], 1u);
      }
      __syncthreads();
      u32 myc = (tid < p.NB) ? hist[tid] : 0;
      scanA[tid] = myc;
      __syncthreads();
      for (int off = 1; off < p.NB; off <<= 1) {
        u32 t2 = scanA[tid] + ((tid >= off) ? scanA[tid - off] : 0);
        __syncthreads();
        scanA[tid] = t2;
        __syncthreads();
      }
      u32 excl = scanA[tid] - myc;
      u32* rt = p.runTab + (size_t)a * (p.NB + 1);
      if (tid < p.NB) { rt[tid] = excl; hist[tid] = excl; }
      if (tid == 0) rt[p.NB] = (u32)len;
      __syncthreads();
      for (int i = e0 + tid; i < e1; i += 512) {
        int s = p.esrc[i], d = p.edst[i];
        u32 q = atomicAdd(&hist[d >> BKT_SH], 1u);
        stage[q] = (u32)s | ((u32)(d & (BKT - 1)) << 16);
      }
      __syncthreads();
      u32* op = p.part + (size_t)a * EPB;
      for (int j = tid; j < len; j += 512) op[j] = stage[j];
    }
  }
  grid.sync();

  // ---------------- P2: partb — ELL build (src-bucket-sorted) + fused xscale ---
  {
    u16* slice  = (u16*)smem;              // 16384 B
    u32* cnt2   = (u32*)(smem + 16384);    // 8704 B (stride 17)
    u32* roff   = (u32*)(smem + 25088);    // 2052 B
    u32* rbase  = (u32*)(smem + 27140);    // 2048 B
    u16* runid  = (u16*)(smem + 29188);    // 6144 B
    u32* pstage = (u32*)(smem + 35332);    // 12288 B
    u32* scanB  = (u32*)(smem + 47620);    // 2048 B
    for (int b = blockIdx.x; b < p.NB; b += gridDim.x) {
      __syncthreads();                     // protect slice across iterations
      int base = b * BKT;
      int hi = min(BKT, p.N - base);
      if (hi <= 0) continue;
      u32 nv = ((u32)p.N << 16) | (u32)p.N;
      u32* s32 = (u32*)slice;
      for (int j = tid; j < BKT * (ELL_PAD / 2); j += 512) s32[j] = nv;
      for (int j = tid; j < BKT * 17; j += 512) cnt2[j] = 0;
      u32 mylen = 0;
      if (tid < p.NA) {
        u32 s = p.runTab[(size_t)tid * (p.NB + 1) + b];
        u32 e = p.runTab[(size_t)tid * (p.NB + 1) + b + 1];
        mylen = e - s;
        rbase[tid] = (u32)tid * EPB + s;
      }
      scanB[tid] = mylen;
      __syncthreads();
      for (int off = 1; off < p.NA + 1; off <<= 1) {
        u32 t2 = scanB[tid] + ((tid >= off) ? scanB[tid - off] : 0);
        __syncthreads();
        scanB[tid] = t2;
        __syncthreads();
      }
      if (tid <= p.NA) roff[tid] = scanB[tid] - mylen;   // roff[NA] = total
      __syncthreads();
      int T = (int)roff[p.NA];
      for (int a = tid; a < p.NA; a += 512) {
        u32 s0 = roff[a];
        u32 l = roff[a + 1] - s0;
        for (u32 k = 0; k < l; k++)
          if (s0 + k < RUNCAP) runid[s0 + k] = (u16)a;
      }
      __syncthreads();
      // pass A: read part once, stage pair, count (row, srcbucket)
      for (int i = tid; i < T; i += 512) {
        int a;
        if (i < RUNCAP) a = runid[i];
        else {
          int lo = 0, hh = p.NA;
          while (hh - lo > 1) { int mid = (lo + hh) >> 1; if (roff[mid] <= (u32)i) lo = mid; else hh = mid; }
          a = lo;
        }
        u32 pair = p.part[(size_t)rbase[a] + ((u32)i - roff[a])];
        if (i < RUNCAP) pstage[i] = pair;
        u32 dl = pair >> 16;
        u32 src = pair & 0xFFFFu;
        atomicAdd(&cnt2[dl * 17 + (src >> 12)], 1u);
      }
      __syncthreads();
      if (tid < BKT) {
        u32 run = 0;
        for (int bk = 0; bk < 16; bk++) {
          u32 t2 = cnt2[tid * 17 + bk];
          cnt2[tid * 17 + bk] = run;
          run += t2;
        }
        if (tid < hi) p.deg_in[base + tid] = (int)run;
      }
      __syncthreads();
      // pass B: place at bucket cursors -> row sorted by src bucket
      for (int i = tid; i < T; i += 512) {
        u32 pair;
        if (i < RUNCAP) pair = pstage[i];
        else {
          int lo = 0, hh = p.NA;
          while (hh - lo > 1) { int mid = (lo + hh) >> 1; if (roff[mid] <= (u32)i) lo = mid; else hh = mid; }
          pair = p.part[(size_t)rbase[lo] + ((u32)i - roff[lo])];
        }
        u32 dl = pair >> 16;
        u32 src = pair & 0xFFFFu;
        u32 q = atomicAdd(&cnt2[dl * 17 + (src >> 12)], 1u);
        if (q < ELL_PAD) slice[dl * ELL_PAD + q] = (u16)src;
      }
      __syncthreads();
      u32* eg = (u32*)(p.ell + (size_t)base * ELL_PAD);
      for (int j = tid; j < hi * (ELL_PAD / 2); j += 512) eg[j] = s32[j];
      // fused xscale for rows [base, base+hi)
      float* sc = (float*)scanB;
      if (tid < hi) {
        int d = p.deg_out[base + tid]; if (d < 1) d = 1;
        sc[tid] = rsqrtf((float)d);
      }
      __syncthreads();
      __half2* xh2 = (__half2*)p.xh0;
      for (int j = tid; j < hi * 64; j += 512) {
        int r = j >> 6, c = j & 63;
        float s = sc[r];
        float2 v = ((const float2*)p.x)[(size_t)(base + r) * 64 + c];
        xh2[(size_t)(base + r) * 64 + c] = __floats2half2_rn(v.x * s, v.y * s);
      }
    }
  }

  // ---------------- P3..P5: layers (r4-proven 16-row fused body) ---------------
  for (int l = 0; l < p.L; l++) {
    grid.sync();
    const _Float16* xin = (l & 1) ? p.xh1 : p.xh0;
    bool last = (l == p.L - 1);
    __half* o16 = last ? nullptr : (__half*)((l & 1) ? p.xh0 : p.xh1);
    float* o32 = last ? p.outf : nullptr;
    const _Float16* Wh = p.Whi + (size_t)l * 16384;
    const _Float16* Wl = p.Wlo + (size_t)l * 16384;
    const float* bias = p.bs + (size_t)l * 128;
    _Float16* As = (_Float16*)smem;      // 16 x 136 halves = 4352 B
    const int wave = tid >> 6, lane = tid & 63, sub = lane & 15, grp = lane >> 4;
    const int sh = grp << 4;
    const u32 sub16 = (u32)sub * 16u;
    const char* xb = (const char*)xin;

    for (int t = blockIdx.x; t < p.tiles; t += gridDim.x) {
      __syncthreads();                   // protect As across tile iterations
      int rowBase = t * 16;
      // ---- gather: 2 rows per wave, 16 lanes/edge dwordx4, joint x8 MLP
      {
        int r0 = rowBase + wave * 2, r1 = r0 + 1;
        int d0 = (r0 < p.N) ? p.deg_in[r0] : 0;
        int d1 = (r1 < p.N) ? p.deg_in[r1] : 0;
        int l0 = d0 > ELL_PAD ? ELL_PAD : d0;
        int l1 = d1 > ELL_PAD ? ELL_PAD : d1;
        int t0 = (l0 + 3) & ~3;
        int t1 = (l1 + 3) & ~3;
        const u16* ep0 = p.ell + (u32)(r0 < p.N ? r0 : 0) * ELL_PAD;
        const u16* ep1 = p.ell + (u32)(r1 < p.N ? r1 : 0) * ELL_PAD;

        float a0[8] = {0.f, 0.f, 0.f, 0.f, 0.f, 0.f, 0.f, 0.f};
        float a1[8] = {0.f, 0.f, 0.f, 0.f, 0.f, 0.f, 0.f, 0.f};

        int m = t0 < t1 ? t0 : t1;
        int e = 0;
        for (; e + 8 <= m; e += 8) {
          u64 wa0 = *(const u64*)&ep0[e];
          u64 wa1 = *(const u64*)&ep0[e + 4];
          u64 wb0 = *(const u64*)&ep1[e];
          u64 wb1 = *(const u64*)&ep1[e + 4];
          u32 ia0 = ((u32)(wa0 >> sh) & 0xFFFFu) * 256u + sub16;
          u32 ia1 = ((u32)(wa1 >> sh) & 0xFFFFu) * 256u + sub16;
          u32 ib0 = ((u32)(wb0 >> sh) & 0xFFFFu) * 256u + sub16;
          u32 ib1 = ((u32)(wb1 >> sh) & 0xFFFFu) * 256u + sub16;
          half8 va0 = *(const half8*)(xb + ia0);
          half8 va1 = *(const half8*)(xb + ia1);
          half8 vb0 = *(const half8*)(xb + ib0);
          half8 vb1 = *(const half8*)(xb + ib1);
#pragma unroll
          for (int j = 0; j < 8; j++) {
            a0[j] += (float)va0[j] + (float)va1[j];
            a1[j] += (float)vb0[j] + (float)vb1[j];
          }
        }
        for (; e < m; e += 4) {
          u64 wa = *(const u64*)&ep0[e];
          u64 wb = *(const u64*)&ep1[e];
          u32 ia = ((u32)(wa >> sh) & 0xFFFFu) * 256u + sub16;
          u32 ib = ((u32)(wb >> sh) & 0xFFFFu) * 256u + sub16;
          half8 va = *(const half8*)(xb + ia);
          half8 vb = *(const half8*)(xb + ib);
#pragma unroll
          for (int j = 0; j < 8; j++) { a0[j] += (float)va[j]; a1[j] += (float)vb[j]; }
        }
        for (int ea = m; ea < t0; ea += 4) {
          u64 wa = *(const u64*)&ep0[ea];
          u32 ia = ((u32)(wa >> sh) & 0xFFFFu) * 256u + sub16;
          half8 va = *(const half8*)(xb + ia);
#pragma unroll
          for (int j = 0; j < 8; j++) a0[j] += (float)va[j];
        }
        for (int eb = m; eb < t1; eb += 4) {
          u64 wb = *(const u64*)&ep1[eb];
          u32 ib = ((u32)(wb >> sh) & 0xFFFFu) * 256u + sub16;
          half8 vb = *(const half8*)(xb + ib);
#pragma unroll
          for (int j = 0; j < 8; j++) a1[j] += (float)vb[j];
        }

#pragma unroll
        for (int j = 0; j < 8; j++) {
          a0[j] += __shfl_xor(a0[j], 16, 64);
          a0[j] += __shfl_xor(a0[j], 32, 64);
          a1[j] += __shfl_xor(a1[j], 16, 64);
          a1[j] += __shfl_xor(a1[j], 32, 64);
        }

        float si0 = rsqrtf((float)(d0 < 1 ? 1 : d0));
        float si1 = rsqrtf((float)(d1 < 1 ? 1 : d1));
        if (grp == 0) {
          half8 h0, h1;
#pragma unroll
          for (int j = 0; j < 8; j++) {
            h0[j] = (_Float16)(a0[j] * si0);
            h1[j] = (_Float16)(a1[j] * si1);
          }
          *(half8*)&As[(wave * 2 + 0) * 136 + sub * 8] = h0;
          *(half8*)&As[(wave * 2 + 1) * 136 + sub * 8] = h1;
        }
      }
      __syncthreads();

      // ---- GEMM: wave w computes C[0:16, w*16:(w+1)*16]
      f32x4 acc = (f32x4){0.f, 0.f, 0.f, 0.f};
#pragma unroll
      for (int ks = 0; ks < 4; ks++) {
        half8 a = *(const half8*)&As[(size_t)sub * 136 + ks * 32 + grp * 8];
        half8 bh = *(const half8*)&Wh[((wave * 4 + ks) * 64 + lane) * 8];
        half8 bl = *(const half8*)&Wl[((wave * 4 + ks) * 64 + lane) * 8];
        acc = __builtin_amdgcn_mfma_f32_16x16x32_f16(a, bh, acc, 0, 0, 0);
        acc = __builtin_amdgcn_mfma_f32_16x16x32_f16(a, bl, acc, 0, 0, 0);
      }
      // C/D: col = lane&15 (+wave*16), row = grp*4 + reg  [m89-verified mapping]
      const int r0c = rowBase + grp * 4;
      const int col = wave * 16 + sub;
      const float bv = bias[col];
#pragma unroll
      for (int r = 0; r < 4; r++) {
        int row = r0c + r;
        if (row < p.N) {
          float v = fmaxf(acc[r] + bv, 0.f);
          if (o16) {
            int d = p.deg_out[row]; if (d < 1) d = 1;
            o16[(size_t)row * 128 + col] = __float2half(v * rsqrtf((float)d));
          } else {
            o32[(size_t)row * 128 + col] = v;
          }
        }
      }
    }
  }
}

// ---------- launch ----------

extern "C" void kernel_launch(void* const* d_in, const int* in_sizes, int n_in,
                              void* d_out, int out_size, void* d_ws, size_t ws_size,
                              hipStream_t stream) {
  const float* x   = (const float*)d_in[0];
  const float* Ws  = (const float*)d_in[1];
  const float* bs  = (const float*)d_in[2];
  const int* esrc  = (const int*)d_in[3];
  const int* edst  = (const int*)d_in[4];

  const int D = 128;
  const int N = in_sizes[0] / D;
  const int E = in_sizes[3];
  const int L = in_sizes[1] / (D * D);
  const int Npad = ((N + 15) / 16) * 16;
  const int NA = (E + EPB - 1) / EPB;        // 313 for E=640K
  const int NB = (N + BKT - 1) / BKT;        // 391 for N=50K

  // workspace layout, 256B-aligned chunks (no aliasing)
  char* base = (char*)d_ws;
  size_t off = 0;
  auto alloc = [&](size_t bytes) {
    char* p = base + off;
    off = (off + bytes + 255) & ~(size_t)255;
    return p;
  };
  int*      deg_out = (int*)alloc((size_t)N * 4);
  int*      deg_in  = (int*)alloc((size_t)N * 4);
  u16*      ell     = (u16*)alloc((size_t)N * ELL_PAD * 2);
  _Float16* Whi     = (_Float16*)alloc((size_t)L * 16384 * 2);
  _Float16* Wlo     = (_Float16*)alloc((size_t)L * 16384 * 2);
  _Float16* xh0     = (_Float16*)alloc((size_t)(Npad + 16) * 128 * 2);
  _Float16* xh1     = (_Float16*)alloc((size_t)(Npad + 16) * 128 * 2);
  u32*      part    = (u32*)alloc((size_t)NA * EPB * 4);
  u32*      runTab  = (u32*)alloc((size_t)NA * (NB + 1) * 4);

  // cooperative grid: co-resident capacity (cached; host-only queries,
  // graph-capture safe — no allocation, no stream ops)
  static int coopGrid = 0;
  if (coopGrid == 0) {
    int bpc = 0, dev = 0, cus = 0;
    hipGetDevice(&dev);
    hipDeviceGetAttribute(&cus, hipDeviceAttributeMultiprocessorCount, dev);
    hipOccupancyMaxActiveBlocksPerMultiprocessor(&bpc, fused_all, 512, 0);
    if (bpc < 1) bpc = 1;
    if (cus < 1) cus = 256;
    coopGrid = bpc * cus;
  }

  Par par;
  par.x = x; par.Ws = Ws; par.bs = bs; par.esrc = esrc; par.edst = edst;
  par.deg_out = deg_out; par.deg_in = deg_in; par.ell = ell;
  par.Whi = Whi; par.Wlo = Wlo; par.xh0 = xh0; par.xh1 = xh1;
  par.outf = (float*)d_out; par.part = part; par.runTab = runTab;
  par.N = N; par.E = E; par.L = L; par.NA = NA; par.NB = NB;
  par.tiles = Npad / 16; par.packTotal = L * 2048; par.padU32 = 16 * 64;

  void* args[] = { &par };
  hipLaunchCooperativeKernel((const void*)fused_all, dim3(coopGrid), dim3(512),
                             args, 0, stream);
}

// Round 9
// 306.595 us; speedup vs baseline: 1.5829x; 1.5829x over previous
//
#include <hip/hip_runtime.h>
#include <hip/hip_fp16.h>

typedef __attribute__((ext_vector_type(8))) _Float16 half8;
typedef __attribute__((ext_vector_type(4))) float f32x4;
typedef unsigned int u32;
typedef unsigned short u16;
typedef unsigned long long u64;

#define ELL_PAD 64
#define BKT 128          // nodes per dst-bucket (partb LDS slice = 128*64*2B = 16 KB)
#define BKT_SH 7
#define EPB 2048         // edges per parta block (LDS stage = 8 KB)
#define NAMAX 512        // max parta blocks supported by partb's LDS run tables
#define RUNCAP 3072      // staged-pairs capacity (bucket load ~1637 +- 40)

// ---------- K1: zero deg_out + phantom pad rows of xh + pack W ----------
// Pack layout (B-fragment order for mfma_f32_16x16x32_f16):
// elem j of (layer,ntile,kstep,lane) = W[k=kstep*32+(lane>>4)*8+j][n=ntile*16+(lane&15)]

__global__ __launch_bounds__(256) void initpack(int* __restrict__ deg_out,
                                                u32* __restrict__ xz0,
                                                u32* __restrict__ xz1,
                                                const float* __restrict__ Ws,
                                                _Float16* __restrict__ Whi,
                                                _Float16* __restrict__ Wlo,
                                                int N, int padU32, int zb, int packTotal) {
  int b = blockIdx.x;
  if (b < zb) {
    int i = b * 256 + threadIdx.x;
    if (i < N) deg_out[i] = 0;
    if (b == 0) {
      for (int j = threadIdx.x; j < padU32; j += 256) { xz0[j] = 0; xz1[j] = 0; }
    }
    return;
  }
  int i = (b - zb) * 256 + threadIdx.x;
  if (i < packTotal) {
    int lane  = i & 63;
    int kstep = (i >> 6) & 3;
    int ntile = (i >> 8) & 7;
    int layer = i >> 11;
    int nn = ntile * 16 + (lane & 15);
    int k0 = kstep * 32 + (lane >> 4) * 8;
    const float* W = Ws + (size_t)layer * 128 * 128;
    size_t base = (size_t)i * 8;
    for (int j = 0; j < 8; j++) {
      float v = W[(k0 + j) * 128 + nn];
      _Float16 hi = (_Float16)v;
      Whi[base + j] = hi;
      Wlo[base + j] = (_Float16)(v - (float)hi);   // exact residual
    }
  }
}

// ---------- K2a: block-local counting sort of edges into dst-buckets ----------

__global__ __launch_bounds__(512) void parta(const int* __restrict__ esrc,
                                             const int* __restrict__ edst,
                                             int* __restrict__ deg_out,
                                             u32* __restrict__ part,
                                             u32* __restrict__ runTab,
                                             int E, int NB) {
  __shared__ u32 hist[512];       // NB+1 <= 512
  __shared__ u32 stage[EPB];      // 8 KB
  __shared__ u32 scanA[512];
  int a = blockIdx.x;
  int e0 = a * EPB;
  int e1 = min(E, e0 + EPB);
  int len = e1 - e0;
  int tid = threadIdx.x;
  if (tid <= NB) hist[tid] = 0;
  __syncthreads();
  for (int i = e0 + tid; i < e1; i += 512) {
    int s = esrc[i];
    int d = edst[i];
    atomicAdd(&deg_out[s], 1);
    atomicAdd(&hist[d >> BKT_SH], 1u);
  }
  __syncthreads();
  u32 myc = (tid < NB) ? hist[tid] : 0;
  scanA[tid] = myc;
  __syncthreads();
  for (int off = 1; off < NB; off <<= 1) {
    u32 t = scanA[tid] + ((tid >= off) ? scanA[tid - off] : 0);
    __syncthreads();
    scanA[tid] = t;
    __syncthreads();
  }
  u32 excl = scanA[tid] - myc;
  u32* rt = runTab + (size_t)a * (NB + 1);
  if (tid < NB) { rt[tid] = excl; hist[tid] = excl; }
  if (tid == 0) rt[NB] = (u32)len;
  __syncthreads();
  for (int i = e0 + tid; i < e1; i += 512) {
    int s = esrc[i];
    int d = edst[i];
    u32 p = atomicAdd(&hist[d >> BKT_SH], 1u);
    stage[p] = (u32)s | ((u32)(d & (BKT - 1)) << 16);
  }
  __syncthreads();
  u32* op = part + (size_t)a * EPB;
  for (int j = tid; j < len; j += 512) op[j] = stage[j];
}

// ---------- K2b: per-bucket ELL build (src-bucket-sorted rows) + fused xscale ----------

__global__ __launch_bounds__(512) void partb(const u32* __restrict__ part,
                                             const u32* __restrict__ runTab,
                                             const float* __restrict__ x,
                                             const int* __restrict__ deg_out,
                                             int* __restrict__ deg_in,
                                             u16* __restrict__ ell,
                                             __half2* __restrict__ xh,
                                             int N, int NA, int NB) {
  __shared__ u16 slice[BKT * ELL_PAD];   // 16 KB
  __shared__ u32 cnt2[BKT * 17];         // 8.7 KB (17 stride: conflict-free prefix)
  __shared__ u32 roff[NAMAX + 1];
  __shared__ u32 rbase[NAMAX];
  __shared__ u16 runid[RUNCAP];          // 6 KB inverse map
  __shared__ u32 pstage[RUNCAP];         // 12 KB staged pairs
  __shared__ u32 scanA[512];
  int b = blockIdx.x;
  int base = b * BKT;
  int hi = min(BKT, N - base);
  if (hi <= 0) return;
  int tid = threadIdx.x;

  u32 nv = ((u32)N << 16) | (u32)N;      // two phantom entries
  u32* s32 = (u32*)slice;
  for (int j = tid; j < BKT * (ELL_PAD / 2); j += 512) s32[j] = nv;
  for (int j = tid; j < BKT * 17; j += 512) cnt2[j] = 0;
  u32 mylen = 0;
  if (tid < NA) {
    u32 s = runTab[(size_t)tid * (NB + 1) + b];
    u32 e = runTab[(size_t)tid * (NB + 1) + b + 1];
    mylen = e - s;
    rbase[tid] = (u32)tid * EPB + s;
  }
  scanA[tid] = mylen;
  __syncthreads();
  for (int off = 1; off < NA + 1; off <<= 1) {
    u32 t = scanA[tid] + ((tid >= off) ? scanA[tid - off] : 0);
    __syncthreads();
    scanA[tid] = t;
    __syncthreads();
  }
  if (tid <= NA) roff[tid] = scanA[tid] - mylen;   // exclusive; roff[NA] = total
  __syncthreads();
  int T = (int)roff[NA];
  for (int a = tid; a < NA; a += 512) {
    u32 s0 = roff[a];
    u32 l  = roff[a + 1] - s0;
    for (u32 k = 0; k < l; k++)
      if (s0 + k < RUNCAP) runid[s0 + k] = (u16)a;
  }
  __syncthreads();
  // pass A: read part once, stage pair, count (row, srcbucket)
  for (int i = tid; i < T; i += 512) {
    int a;
    if (i < RUNCAP) a = runid[i];
    else {
      int lo = 0, hh = NA;
      while (hh - lo > 1) { int mid = (lo + hh) >> 1; if (roff[mid] <= (u32)i) lo = mid; else hh = mid; }
      a = lo;
    }
    u32 pair = part[(size_t)rbase[a] + ((u32)i - roff[a])];
    if (i < RUNCAP) pstage[i] = pair;
    u32 dl  = pair >> 16;
    u32 src = pair & 0xFFFFu;
    atomicAdd(&cnt2[dl * 17 + (src >> 12)], 1u);
  }
  __syncthreads();
  // per-row exclusive prefix over the 16 src-buckets; emit deg_in
  if (tid < BKT) {
    u32 run = 0;
    for (int bk = 0; bk < 16; bk++) {
      u32 t = cnt2[tid * 17 + bk];
      cnt2[tid * 17 + bk] = run;
      run += t;
    }
    if (tid < hi) deg_in[base + tid] = (int)run;
  }
  __syncthreads();
  // pass B: place at bucket cursors -> row sorted by src bucket
  for (int i = tid; i < T; i += 512) {
    u32 pair;
    if (i < RUNCAP) pair = pstage[i];
    else {
      int lo = 0, hh = NA;
      while (hh - lo > 1) { int mid = (lo + hh) >> 1; if (roff[mid] <= (u32)i) lo = mid; else hh = mid; }
      pair = part[(size_t)rbase[lo] + ((u32)i - roff[lo])];
    }
    u32 dl  = pair >> 16;
    u32 src = pair & 0xFFFFu;
    u32 p = atomicAdd(&cnt2[dl * 17 + (src >> 12)], 1u);
    if (p < ELL_PAD) slice[dl * ELL_PAD + p] = (u16)src;
  }
  __syncthreads();
  u32* eg = (u32*)(ell + (size_t)base * ELL_PAD);
  for (int j = tid; j < hi * (ELL_PAD / 2); j += 512) eg[j] = s32[j];
  // ---- fused xscale for rows [base, base+hi)
  float* sc = (float*)scanA;
  if (tid < hi) {
    int d = deg_out[base + tid]; if (d < 1) d = 1;
    sc[tid] = rsqrtf((float)d);
  }
  __syncthreads();
  for (int j = tid; j < hi * 64; j += 512) {
    int r = j >> 6, c = j & 63;
    float s = sc[r];
    float2 v = ((const float2*)x)[(size_t)(base + r) * 64 + c];
    xh[(size_t)(base + r) * 64 + c] = __floats2half2_rn(v.x * s, v.y * s);
  }
}

// ---------- K4a: D-SPLIT barrier-free gather (4 passes x 32-dim strips) ----------
// Pass q (blockIdx.y) gathers only bytes [q*64, q*64+64) of each source row:
// per-pass working set = 3.2 MB -> fits the 4 MiB per-XCD L2 (each XCD holds
// its own copy). Pass-major dispatch (x fastest) keeps the chip inside one
// strip at a time. Index packs, edge order, and the pairwise (e, e+4)
// summation tree are IDENTICAL to the r7 gather per dim -> bit-identical
// output. Each lane loads 4 B (__half2) instead of 16 B.

__global__ __launch_bounds__(256) void gathq(const _Float16* __restrict__ xh,
                                             const int* __restrict__ deg_in,
                                             const u16* __restrict__ ell,
                                             _Float16* __restrict__ agg, int n) {
  const int wave = (int)threadIdx.x >> 6;
  const int lane = (int)threadIdx.x & 63;
  const int sub  = lane & 15;
  const int grp  = lane >> 4;
  const int sh   = grp << 4;
  const int q    = blockIdx.y;               // strip index, 0..3
  const u32 sub4 = (u32)q * 64u + (u32)sub * 4u;  // byte offset within the row
  const char* __restrict__ xb = (const char*)xh;

  int r0 = blockIdx.x * 8 + wave * 2, r1 = r0 + 1;
  int d0 = (r0 < n) ? deg_in[r0] : 0;
  int d1 = (r1 < n) ? deg_in[r1] : 0;
  int l0 = d0 > ELL_PAD ? ELL_PAD : d0;
  int l1 = d1 > ELL_PAD ? ELL_PAD : d1;
  int t0 = (l0 + 3) & ~3;
  int t1 = (l1 + 3) & ~3;
  const u16* ep0 = ell + (u32)(r0 < n ? r0 : 0) * ELL_PAD;
  const u16* ep1 = ell + (u32)(r1 < n ? r1 : 0) * ELL_PAD;

  float a0x = 0.f, a0y = 0.f, a1x = 0.f, a1y = 0.f;

  int m = t0 < t1 ? t0 : t1;
  int e = 0;
  for (; e + 8 <= m; e += 8) {
    u64 wa0 = *(const u64*)&ep0[e];
    u64 wa1 = *(const u64*)&ep0[e + 4];
    u64 wb0 = *(const u64*)&ep1[e];
    u64 wb1 = *(const u64*)&ep1[e + 4];
    u32 ia0 = ((u32)(wa0 >> sh) & 0xFFFFu) * 256u + sub4;
    u32 ia1 = ((u32)(wa1 >> sh) & 0xFFFFu) * 256u + sub4;
    u32 ib0 = ((u32)(wb0 >> sh) & 0xFFFFu) * 256u + sub4;
    u32 ib1 = ((u32)(wb1 >> sh) & 0xFFFFu) * 256u + sub4;
    float2 va0 = __half22float2(*(const __half2*)(xb + ia0));
    float2 va1 = __half22float2(*(const __half2*)(xb + ia1));
    float2 vb0 = __half22float2(*(const __half2*)(xb + ib0));
    float2 vb1 = __half22float2(*(const __half2*)(xb + ib1));
    a0x += va0.x + va1.x; a0y += va0.y + va1.y;
    a1x += vb0.x + vb1.x; a1y += vb0.y + vb1.y;
  }
  for (; e < m; e += 4) {
    u64 wa = *(const u64*)&ep0[e];
    u64 wb = *(const u64*)&ep1[e];
    u32 ia = ((u32)(wa >> sh) & 0xFFFFu) * 256u + sub4;
    u32 ib = ((u32)(wb >> sh) & 0xFFFFu) * 256u + sub4;
    float2 va = __half22float2(*(const __half2*)(xb + ia));
    float2 vb = __half22float2(*(const __half2*)(xb + ib));
    a0x += va.x; a0y += va.y;
    a1x += vb.x; a1y += vb.y;
  }
  for (int ea = m; ea < t0; ea += 4) {
    u64 wa = *(const u64*)&ep0[ea];
    u32 ia = ((u32)(wa >> sh) & 0xFFFFu) * 256u + sub4;
    float2 va = __half22float2(*(const __half2*)(xb + ia));
    a0x += va.x; a0y += va.y;
  }
  for (int eb = m; eb < t1; eb += 4) {
    u64 wb = *(const u64*)&ep1[eb];
    u32 ib = ((u32)(wb >> sh) & 0xFFFFu) * 256u + sub4;
    float2 vb = __half22float2(*(const __half2*)(xb + ib));
    a1x += vb.x; a1y += vb.y;
  }

  // combine the 4 grp partials (lane bits 4,5)
  a0x += __shfl_xor(a0x, 16, 64); a0x += __shfl_xor(a0x, 32, 64);
  a0y += __shfl_xor(a0y, 16, 64); a0y += __shfl_xor(a0y, 32, 64);
  a1x += __shfl_xor(a1x, 16, 64); a1x += __shfl_xor(a1x, 32, 64);
  a1y += __shfl_xor(a1y, 16, 64); a1y += __shfl_xor(a1y, 32, 64);

  float si0 = rsqrtf((float)(d0 < 1 ? 1 : d0));
  float si1 = rsqrtf((float)(d1 < 1 ? 1 : d1));
  if (grp == 0) {
    // lane sub writes dims [q*32 + sub*2, +2) of its rows
    *(__half2*)&agg[(size_t)r0 * 128 + q * 32 + sub * 2] =
        __floats2half2_rn(a0x * si0, a0y * si0);
    *(__half2*)&agg[(size_t)r1 * 128 + q * 32 + sub * 2] =
        __floats2half2_rn(a1x * si1, a1y * si1);
  }
}

// ---------- K4b: dense GEMM: out = epilogue(agg @ (Whi+Wlo) + b) ----------

__global__ __launch_bounds__(512) void mm64(const _Float16* __restrict__ agg,
                                            const _Float16* __restrict__ Whi,
                                            const _Float16* __restrict__ Wlo,
                                            const float* __restrict__ bias,
                                            const int* __restrict__ deg_out,
                                            __half* __restrict__ out16,
                                            float* __restrict__ out32, int n) {
  __shared__ _Float16 As[64 * 136];   // 17 KB
  const int wave = (int)threadIdx.x >> 6;
  const int lane = (int)threadIdx.x & 63;
  const int sub  = lane & 15;
  const int grp  = lane >> 4;
  const int rowBase = blockIdx.x * 64;

  for (int j = threadIdx.x; j < 64 * 16; j += 512) {
    int r = j >> 4, c = j & 15;
    *(half8*)&As[r * 136 + c * 8] =
        *(const half8*)&agg[(size_t)(rowBase + r) * 128 + c * 8];
  }
  half8 wh[4], wl[4];
#pragma unroll
  for (int ks = 0; ks < 4; ks++) {
    wh[ks] = *(const half8*)&Whi[((wave * 4 + ks) * 64 + lane) * 8];
    wl[ks] = *(const half8*)&Wlo[((wave * 4 + ks) * 64 + lane) * 8];
  }
  __syncthreads();

  const int col = wave * 16 + sub;
  const float bv = bias[col];
#pragma unroll
  for (int rt = 0; rt < 4; rt++) {
    f32x4 acc = (f32x4){0.f, 0.f, 0.f, 0.f};
#pragma unroll
    for (int ks = 0; ks < 4; ks++) {
      half8 a = *(const half8*)&As[(rt * 16 + sub) * 136 + ks * 32 + grp * 8];
      acc = __builtin_amdgcn_mfma_f32_16x16x32_f16(a, wh[ks], acc, 0, 0, 0);
      acc = __builtin_amdgcn_mfma_f32_16x16x32_f16(a, wl[ks], acc, 0, 0, 0);
    }
    // C/D: col = lane&15 (+wave*16), row = grp*4 + reg  [m89-verified mapping]
    int r0c = rowBase + rt * 16 + grp * 4;
#pragma unroll
    for (int r = 0; r < 4; r++) {
      int row = r0c + r;
      if (row < n) {
        float v = fmaxf(acc[r] + bv, 0.f);
        if (out16) {
          int d = deg_out[row]; if (d < 1) d = 1;
          out16[(size_t)row * 128 + col] = __float2half(v * rsqrtf((float)d));
        } else {
          out32[(size_t)row * 128 + col] = v;
        }
      }
    }
  }
}

// ---------- launch ----------

extern "C" void kernel_launch(void* const* d_in, const int* in_sizes, int n_in,
                              void* d_out, int out_size, void* d_ws, size_t ws_size,
                              hipStream_t stream) {
  const float* x   = (const float*)d_in[0];
  const float* Ws  = (const float*)d_in[1];
  const float* bs  = (const float*)d_in[2];
  const int* esrc  = (const int*)d_in[3];
  const int* edst  = (const int*)d_in[4];

  const int D = 128;
  const int N = in_sizes[0] / D;
  const int E = in_sizes[3];
  const int L = in_sizes[1] / (D * D);
  const int Npad = ((N + 63) / 64) * 64;     // multiple of 64 (mm64 tile) and 8
  const int NA = (E + EPB - 1) / EPB;        // parta blocks (313 for E=640K)
  const int NB = (N + BKT - 1) / BKT;        // buckets (391 for N=50K)

  // workspace layout, 256B-aligned chunks (no aliasing)
  char* base = (char*)d_ws;
  size_t off = 0;
  auto alloc = [&](size_t bytes) {
    char* p = base + off;
    off = (off + bytes + 255) & ~(size_t)255;
    return p;
  };
  int*      deg_out = (int*)alloc((size_t)N * 4);
  int*      deg_in  = (int*)alloc((size_t)N * 4);
  u16*      ell     = (u16*)alloc((size_t)N * ELL_PAD * 2);
  _Float16* Whi     = (_Float16*)alloc((size_t)L * 16384 * 2);
  _Float16* Wlo     = (_Float16*)alloc((size_t)L * 16384 * 2);
  _Float16* xh0     = (_Float16*)alloc((size_t)(Npad + 16) * 128 * 2);
  _Float16* xh1     = (_Float16*)alloc((size_t)(Npad + 16) * 128 * 2);
  _Float16* agg     = (_Float16*)alloc((size_t)Npad * 128 * 2);
  u32*      part    = (u32*)alloc((size_t)NA * EPB * 4);
  u32*      runTab  = (u32*)alloc((size_t)NA * (NB + 1) * 4);

  const int zb = (N + 255) / 256;
  const int packTotal = L * 2048;
  const int packB = (packTotal + 255) / 256;
  const int padU32 = 16 * 64;   // 16 phantom rows x 128 halves = 1024 u32/buffer

  initpack<<<dim3(zb + packB), dim3(256), 0, stream>>>(
      deg_out,
      (u32*)(xh0 + (size_t)N * 128), (u32*)(xh1 + (size_t)N * 128),
      Ws, Whi, Wlo, N, padU32, zb, packTotal);
  parta<<<dim3(NA), dim3(512), 0, stream>>>(
      esrc, edst, deg_out, part, runTab, E, NB);
  partb<<<dim3(NB), dim3(512), 0, stream>>>(
      part, runTab, x, deg_out, deg_in, ell, (__half2*)xh0, N, NA, NB);

  float* outf = (float*)d_out;
  _Float16* ping[2] = {xh0, xh1};

  for (int l = 0; l < L; l++) {
    bool last = (l == L - 1);
    gathq<<<dim3(Npad / 8, 4), dim3(256), 0, stream>>>(
        (const _Float16*)ping[l & 1], deg_in, ell, agg, N);
    mm64<<<dim3(Npad / 64), dim3(512), 0, stream>>>(
        agg, Whi + (size_t)l * 16384, Wlo + (size_t)l * 16384,
        bs + (size_t)l * D, deg_out,
        last ? nullptr : (__half*)ping[(l + 1) & 1],
        last ? outf : nullptr, N);
  }
}

// Round 10
// 241.781 us; speedup vs baseline: 2.0072x; 1.2681x over previous
//
#include <hip/hip_runtime.h>
#include <hip/hip_fp16.h>

typedef __attribute__((ext_vector_type(8))) _Float16 half8;
typedef __attribute__((ext_vector_type(4))) float f32x4;
typedef unsigned int u32;
typedef unsigned short u16;
typedef unsigned long long u64;

#define ELL_PAD 64
#define BKT 64           // nodes per dst-bucket -> 782 partb blocks (6.1 waves/SIMD)
#define BKT_SH 6
#define EPB 1024         // edges per parta block -> 625 parta blocks (4.9 waves/SIMD)
#define NAMAX 640        // max parta blocks supported by partb's LDS run tables
#define RUNCAP 1536      // staged-pairs capacity (bucket load ~819 +- 29; +25 sigma)

// ---------- K1: zero deg_out + phantom pad rows of xh + pack W ----------
// Pack layout (B-fragment order for mfma_f32_16x16x32_f16):
// elem j of (layer,ntile,kstep,lane) = W[k=kstep*32+(lane>>4)*8+j][n=ntile*16+(lane&15)]

__global__ __launch_bounds__(256) void initpack(int* __restrict__ deg_out,
                                                u32* __restrict__ xz0,
                                                u32* __restrict__ xz1,
                                                const float* __restrict__ Ws,
                                                _Float16* __restrict__ Whi,
                                                _Float16* __restrict__ Wlo,
                                                int N, int padU32, int zb, int packTotal) {
  int b = blockIdx.x;
  if (b < zb) {
    int i = b * 256 + threadIdx.x;
    if (i < N) deg_out[i] = 0;
    if (b == 0) {
      for (int j = threadIdx.x; j < padU32; j += 256) { xz0[j] = 0; xz1[j] = 0; }
    }
    return;
  }
  int i = (b - zb) * 256 + threadIdx.x;
  if (i < packTotal) {
    int lane  = i & 63;
    int kstep = (i >> 6) & 3;
    int ntile = (i >> 8) & 7;
    int layer = i >> 11;
    int nn = ntile * 16 + (lane & 15);
    int k0 = kstep * 32 + (lane >> 4) * 8;
    const float* W = Ws + (size_t)layer * 128 * 128;
    size_t base = (size_t)i * 8;
    for (int j = 0; j < 8; j++) {
      float v = W[(k0 + j) * 128 + nn];
      _Float16 hi = (_Float16)v;
      Whi[base + j] = hi;
      Wlo[base + j] = (_Float16)(v - (float)hi);   // exact residual
    }
  }
}

// ---------- K2a: block-local counting sort of edges into dst-buckets ----------
// 625 blocks x 512 thr (4.9 waves/SIMD vs 0.78 at EPB=2048 — the build was
// latency-exposed below 1 wave/SIMD). Scan generalized to 2-elem/thread
// Hillis-Steele since NB=782 > 512.

__global__ __launch_bounds__(512) void parta(const int* __restrict__ esrc,
                                             const int* __restrict__ edst,
                                             int* __restrict__ deg_out,
                                             u32* __restrict__ part,
                                             u32* __restrict__ runTab,
                                             int E, int NB) {
  __shared__ u32 hist[1024];      // NB+1 <= 1024
  __shared__ u32 stage[EPB];      // 4 KB
  __shared__ u32 scanA[512];
  int a = blockIdx.x;
  int e0 = a * EPB;
  int e1 = min(E, e0 + EPB);
  int len = e1 - e0;
  int tid = threadIdx.x;
  for (int j = tid; j <= NB; j += 512) hist[j] = 0;
  __syncthreads();
  // pass 1: histogram + deg_out atomics
  for (int i = e0 + tid; i < e1; i += 512) {
    int s = esrc[i];
    int d = edst[i];
    atomicAdd(&deg_out[s], 1);
    atomicAdd(&hist[d >> BKT_SH], 1u);
  }
  __syncthreads();
  // 2-elem/thread exclusive scan over NB buckets
  int i0 = 2 * tid, i1 = 2 * tid + 1;
  u32 c0 = (i0 < NB) ? hist[i0] : 0;
  u32 c1 = (i1 < NB) ? hist[i1] : 0;
  u32 s2 = c0 + c1;
  scanA[tid] = s2;
  __syncthreads();
  for (int off = 1; off < 512; off <<= 1) {
    u32 t2 = scanA[tid] + ((tid >= off) ? scanA[tid - off] : 0);
    __syncthreads();
    scanA[tid] = t2;
    __syncthreads();
  }
  u32 base = scanA[tid] - s2;
  u32* rt = runTab + (size_t)a * (NB + 1);
  if (i0 < NB) { rt[i0] = base;      hist[i0] = base; }
  if (i1 < NB) { rt[i1] = base + c0; hist[i1] = base + c0; }
  if (tid == 0) rt[NB] = (u32)len;
  __syncthreads();
  // pass 2: place into LDS staging ordered by bucket (edges L2-hot)
  for (int i = e0 + tid; i < e1; i += 512) {
    int s = esrc[i];
    int d = edst[i];
    u32 p = atomicAdd(&hist[d >> BKT_SH], 1u);
    stage[p] = (u32)s | ((u32)(d & (BKT - 1)) << 16);
  }
  __syncthreads();
  // pass 3: dense coalesced write
  u32* op = part + (size_t)a * EPB;
  for (int j = tid; j < len; j += 512) op[j] = stage[j];
}

// ---------- K2b: per-bucket ELL build (src-bucket-sorted rows) + fused xscale ----------
// 782 blocks x 512 thr, ~29 KB LDS (was 391 blocks / 48.5 KB). Rows sorted by
// src>>12 (1 MB granularity) so resident layer waves sweep xh in a sliding
// L2-sized window. Run scan is 2-elem/thread (NA=625 > 512).

__global__ __launch_bounds__(512) void partb(const u32* __restrict__ part,
                                             const u32* __restrict__ runTab,
                                             const float* __restrict__ x,
                                             const int* __restrict__ deg_out,
                                             int* __restrict__ deg_in,
                                             u16* __restrict__ ell,
                                             __half2* __restrict__ xh,
                                             int N, int NA, int NB) {
  __shared__ u16 slice[BKT * ELL_PAD];   // 8 KB
  __shared__ u32 cnt2[BKT * 17];         // 4.3 KB (17 stride: conflict-free prefix)
  __shared__ u32 roff[NAMAX + 1];
  __shared__ u32 rbase[NAMAX];
  __shared__ u16 runid[RUNCAP];          // 3 KB inverse map
  __shared__ u32 pstage[RUNCAP];         // 6 KB staged pairs
  __shared__ u32 scanB[512];
  int b = blockIdx.x;
  int base = b * BKT;
  int hi = min(BKT, N - base);
  if (hi <= 0) return;
  int tid = threadIdx.x;

  u32 nv = ((u32)N << 16) | (u32)N;      // two phantom entries
  u32* s32 = (u32*)slice;
  for (int j = tid; j < BKT * (ELL_PAD / 2); j += 512) s32[j] = nv;
  for (int j = tid; j < BKT * 17; j += 512) cnt2[j] = 0;
  // 2-elem/thread run-length load + scan
  int a0 = 2 * tid, a1 = 2 * tid + 1;
  u32 l0 = 0, l1 = 0;
  if (a0 < NA) {
    u32 s = runTab[(size_t)a0 * (NB + 1) + b];
    u32 e = runTab[(size_t)a0 * (NB + 1) + b + 1];
    l0 = e - s;
    rbase[a0] = (u32)a0 * EPB + s;
  }
  if (a1 < NA) {
    u32 s = runTab[(size_t)a1 * (NB + 1) + b];
    u32 e = runTab[(size_t)a1 * (NB + 1) + b + 1];
    l1 = e - s;
    rbase[a1] = (u32)a1 * EPB + s;
  }
  u32 s2 = l0 + l1;
  scanB[tid] = s2;
  __syncthreads();
  for (int off = 1; off < 512; off <<= 1) {
    u32 t2 = scanB[tid] + ((tid >= off) ? scanB[tid - off] : 0);
    __syncthreads();
    scanB[tid] = t2;
    __syncthreads();
  }
  u32 pbase = scanB[tid] - s2;
  if (a0 < NA) roff[a0] = pbase;
  if (a1 < NA) roff[a1] = pbase + l0;
  if (tid == 511) roff[NA] = scanB[511];   // total
  __syncthreads();
  int T = (int)roff[NA];
  // inverse map: runid[i] = run containing flattened item i
  for (int a = tid; a < NA; a += 512) {
    u32 s0 = roff[a];
    u32 l = roff[a + 1] - s0;
    for (u32 k = 0; k < l; k++)
      if (s0 + k < RUNCAP) runid[s0 + k] = (u16)a;
  }
  __syncthreads();
  // pass A: read part once, stage pair, count (row, srcbucket)
  for (int i = tid; i < T; i += 512) {
    int a;
    if (i < RUNCAP) a = runid[i];
    else {
      int lo = 0, hh = NA;
      while (hh - lo > 1) { int mid = (lo + hh) >> 1; if (roff[mid] <= (u32)i) lo = mid; else hh = mid; }
      a = lo;
    }
    u32 pair = part[(size_t)rbase[a] + ((u32)i - roff[a])];
    if (i < RUNCAP) pstage[i] = pair;
    u32 dl = pair >> 16;
    u32 src = pair & 0xFFFFu;
    atomicAdd(&cnt2[dl * 17 + (src >> 12)], 1u);
  }
  __syncthreads();
  // per-row exclusive prefix over the 16 src-buckets; emit deg_in
  if (tid < BKT) {
    u32 run = 0;
    for (int bk = 0; bk < 16; bk++) {
      u32 t2 = cnt2[tid * 17 + bk];
      cnt2[tid * 17 + bk] = run;
      run += t2;
    }
    if (tid < hi) deg_in[base + tid] = (int)run;
  }
  __syncthreads();
  // pass B: place at bucket cursors -> row sorted by src bucket
  for (int i = tid; i < T; i += 512) {
    u32 pair;
    if (i < RUNCAP) pair = pstage[i];
    else {
      int lo = 0, hh = NA;
      while (hh - lo > 1) { int mid = (lo + hh) >> 1; if (roff[mid] <= (u32)i) lo = mid; else hh = mid; }
      pair = part[(size_t)rbase[lo] + ((u32)i - roff[lo])];
    }
    u32 dl = pair >> 16;
    u32 src = pair & 0xFFFFu;
    u32 p = atomicAdd(&cnt2[dl * 17 + (src >> 12)], 1u);
    if (p < ELL_PAD) slice[dl * ELL_PAD + p] = (u16)src;
  }
  __syncthreads();
  u32* eg = (u32*)(ell + (size_t)base * ELL_PAD);
  for (int j = tid; j < hi * (ELL_PAD / 2); j += 512) eg[j] = s32[j];
  // ---- fused xscale for rows [base, base+hi)
  float* sc = (float*)scanB;
  if (tid < hi) {
    int d = deg_out[base + tid]; if (d < 1) d = 1;
    sc[tid] = rsqrtf((float)d);
  }
  __syncthreads();
  for (int j = tid; j < hi * 64; j += 512) {
    int r = j >> 6, c = j & 63;
    float s = sc[r];
    float2 v = ((const float2*)x)[(size_t)(base + r) * 64 + c];
    xh[(size_t)(base + r) * 64 + c] = __floats2half2_rn(v.x * s, v.y * s);
  }
}

// ---------- K4: fused layer — 16-row tile, 8 waves (r4-proven body) ----------
// 16 lanes per edge, dwordx4 (16 B/lane) gathers; ELL pad slots hold phantom
// index N whose xh row is zeroed, so no scalar tails. Rows are src-bucket
// sorted (partb), so resident waves sweep xh in a sliding L2-sized window.

__global__ __launch_bounds__(512) void layer16(const _Float16* __restrict__ xh,
                                               const int* __restrict__ deg_in,
                                               const u16* __restrict__ ell,
                                               const _Float16* __restrict__ Whi,
                                               const _Float16* __restrict__ Wlo,
                                               const float* __restrict__ bias,
                                               const int* __restrict__ deg_out,
                                               __half* __restrict__ out16,
                                               float* __restrict__ out32, int n) {
  __shared__ _Float16 As[16 * 136];   // 4.25 KB; stride 136 halves
  const int wave = threadIdx.x >> 6;
  const int lane = threadIdx.x & 63;
  const int sub  = lane & 15;
  const int grp  = lane >> 4;
  const int sh   = grp << 4;          // u64 shift to extract this grp's edge index
  const u32 sub16 = (u32)sub * 16u;   // byte offset within a 256 B row
  const int rowBase = blockIdx.x * 16;
  const char* __restrict__ xb = (const char*)xh;

  // ---- gather phase: 2 rows per wave
  {
    int r0 = rowBase + wave * 2, r1 = r0 + 1;
    int d0 = (r0 < n) ? deg_in[r0] : 0;
    int d1 = (r1 < n) ? deg_in[r1] : 0;
    int l0 = d0 > ELL_PAD ? ELL_PAD : d0;
    int l1 = d1 > ELL_PAD ? ELL_PAD : d1;
    int t0 = (l0 + 3) & ~3;           // padded trip counts (multiple of 4)
    int t1 = (l1 + 3) & ~3;
    const u16* ep0 = ell + (u32)(r0 < n ? r0 : 0) * ELL_PAD;
    const u16* ep1 = ell + (u32)(r1 < n ? r1 : 0) * ELL_PAD;

    float a0[8] = {0.f, 0.f, 0.f, 0.f, 0.f, 0.f, 0.f, 0.f};
    float a1[8] = {0.f, 0.f, 0.f, 0.f, 0.f, 0.f, 0.f, 0.f};

    int m = t0 < t1 ? t0 : t1;
    int e = 0;
    // joint x8: 8 dwordx4 gathers in flight
    for (; e + 8 <= m; e += 8) {
      u64 wa0 = *(const u64*)&ep0[e];
      u64 wa1 = *(const u64*)&ep0[e + 4];
      u64 wb0 = *(const u64*)&ep1[e];
      u64 wb1 = *(const u64*)&ep1[e + 4];
      u32 ia0 = ((u32)(wa0 >> sh) & 0xFFFFu) * 256u + sub16;
      u32 ia1 = ((u32)(wa1 >> sh) & 0xFFFFu) * 256u + sub16;
      u32 ib0 = ((u32)(wb0 >> sh) & 0xFFFFu) * 256u + sub16;
      u32 ib1 = ((u32)(wb1 >> sh) & 0xFFFFu) * 256u + sub16;
      half8 va0 = *(const half8*)(xb + ia0);
      half8 va1 = *(const half8*)(xb + ia1);
      half8 vb0 = *(const half8*)(xb + ib0);
      half8 vb1 = *(const half8*)(xb + ib1);
#pragma unroll
      for (int j = 0; j < 8; j++) {
        a0[j] += (float)va0[j] + (float)va1[j];
        a1[j] += (float)vb0[j] + (float)vb1[j];
      }
    }
    // joint x4 remainder
    for (; e < m; e += 4) {
      u64 wa = *(const u64*)&ep0[e];
      u64 wb = *(const u64*)&ep1[e];
      u32 ia = ((u32)(wa >> sh) & 0xFFFFu) * 256u + sub16;
      u32 ib = ((u32)(wb >> sh) & 0xFFFFu) * 256u + sub16;
      half8 va = *(const half8*)(xb + ia);
      half8 vb = *(const half8*)(xb + ib);
#pragma unroll
      for (int j = 0; j < 8; j++) { a0[j] += (float)va[j]; a1[j] += (float)vb[j]; }
    }
    // per-row x4 remainders
    for (int ea = m; ea < t0; ea += 4) {
      u64 wa = *(const u64*)&ep0[ea];
      u32 ia = ((u32)(wa >> sh) & 0xFFFFu) * 256u + sub16;
      half8 va = *(const half8*)(xb + ia);
#pragma unroll
      for (int j = 0; j < 8; j++) a0[j] += (float)va[j];
    }
    for (int eb = m; eb < t1; eb += 4) {
      u64 wb = *(const u64*)&ep1[eb];
      u32 ib = ((u32)(wb >> sh) & 0xFFFFu) * 256u + sub16;
      half8 vb = *(const half8*)(xb + ib);
#pragma unroll
      for (int j = 0; j < 8; j++) a1[j] += (float)vb[j];
    }

    // combine the 4 grp partials (lane bits 4,5)
#pragma unroll
    for (int j = 0; j < 8; j++) {
      a0[j] += __shfl_xor(a0[j], 16, 64);
      a0[j] += __shfl_xor(a0[j], 32, 64);
      a1[j] += __shfl_xor(a1[j], 16, 64);
      a1[j] += __shfl_xor(a1[j], 32, 64);
    }

    float si0 = rsqrtf((float)(d0 < 1 ? 1 : d0));
    float si1 = rsqrtf((float)(d1 < 1 ? 1 : d1));
    if (grp == 0) {
      half8 h0, h1;
#pragma unroll
      for (int j = 0; j < 8; j++) {
        h0[j] = (_Float16)(a0[j] * si0);
        h1[j] = (_Float16)(a1[j] * si1);
      }
      *(half8*)&As[(wave * 2 + 0) * 136 + sub * 8] = h0;
      *(half8*)&As[(wave * 2 + 1) * 136 + sub * 8] = h1;
    }
  }
  __syncthreads();

  // ---- GEMM phase: wave w computes C[0:16, w*16:(w+1)*16]
  f32x4 acc = (f32x4){0.f, 0.f, 0.f, 0.f};
#pragma unroll
  for (int ks = 0; ks < 4; ks++) {
    half8 a  = *(const half8*)&As[(size_t)sub * 136 + ks * 32 + grp * 8];
    half8 bh = *(const half8*)&Whi[((wave * 4 + ks) * 64 + lane) * 8];
    half8 bl = *(const half8*)&Wlo[((wave * 4 + ks) * 64 + lane) * 8];
    acc = __builtin_amdgcn_mfma_f32_16x16x32_f16(a, bh, acc, 0, 0, 0);
    acc = __builtin_amdgcn_mfma_f32_16x16x32_f16(a, bl, acc, 0, 0, 0);
  }

  // C/D: col = lane&15 (+wave*16), row = grp*4 + reg  [m89-verified mapping]
  const int r0c = rowBase + grp * 4;
  const int col = wave * 16 + sub;
  const float bv = bias[col];
#pragma unroll
  for (int r = 0; r < 4; r++) {
    int row = r0c + r;
    if (row < n) {
      float v = fmaxf(acc[r] + bv, 0.f);
      if (out16) {
        int d = deg_out[row]; if (d < 1) d = 1;
        out16[(size_t)row * 128 + col] = __float2half(v * rsqrtf((float)d));
      } else {
        out32[(size_t)row * 128 + col] = v;
      }
    }
  }
}

// ---------- launch ----------

extern "C" void kernel_launch(void* const* d_in, const int* in_sizes, int n_in,
                              void* d_out, int out_size, void* d_ws, size_t ws_size,
                              hipStream_t stream) {
  const float* x   = (const float*)d_in[0];
  const float* Ws  = (const float*)d_in[1];
  const float* bs  = (const float*)d_in[2];
  const int* esrc  = (const int*)d_in[3];
  const int* edst  = (const int*)d_in[4];

  const int D = 128;
  const int N = in_sizes[0] / D;
  const int E = in_sizes[3];
  const int L = in_sizes[1] / (D * D);
  const int Npad = ((N + 15) / 16) * 16;
  const int NA = (E + EPB - 1) / EPB;        // parta blocks (625 for E=640K)
  const int NB = (N + BKT - 1) / BKT;        // buckets (782 for N=50K)

  // workspace layout, 256B-aligned chunks (no aliasing)
  char* base = (char*)d_ws;
  size_t off = 0;
  auto alloc = [&](size_t bytes) {
    char* p = base + off;
    off = (off + bytes + 255) & ~(size_t)255;
    return p;
  };
  int*      deg_out = (int*)alloc((size_t)N * 4);
  int*      deg_in  = (int*)alloc((size_t)N * 4);
  u16*      ell     = (u16*)alloc((size_t)N * ELL_PAD * 2);
  _Float16* Whi     = (_Float16*)alloc((size_t)L * 16384 * 2);
  _Float16* Wlo     = (_Float16*)alloc((size_t)L * 16384 * 2);
  _Float16* xh0     = (_Float16*)alloc((size_t)(Npad + 16) * 128 * 2);
  _Float16* xh1     = (_Float16*)alloc((size_t)(Npad + 16) * 128 * 2);
  u32*      part    = (u32*)alloc((size_t)NA * EPB * 4);
  u32*      runTab  = (u32*)alloc((size_t)NA * (NB + 1) * 4);

  const int zb = (N + 255) / 256;
  const int packTotal = L * 2048;
  const int packB = (packTotal + 255) / 256;
  const int padU32 = 16 * 64;   // 16 phantom rows x 128 halves = 1024 u32/buffer

  initpack<<<dim3(zb + packB), dim3(256), 0, stream>>>(
      deg_out,
      (u32*)(xh0 + (size_t)N * 128), (u32*)(xh1 + (size_t)N * 128),
      Ws, Whi, Wlo, N, padU32, zb, packTotal);
  parta<<<dim3(NA), dim3(512), 0, stream>>>(
      esrc, edst, deg_out, part, runTab, E, NB);
  partb<<<dim3(NB), dim3(512), 0, stream>>>(
      part, runTab, x, deg_out, deg_in, ell, (__half2*)xh0, N, NA, NB);

  float* outf = (float*)d_out;
  _Float16* ping[2] = {xh0, xh1};
  const dim3 lgrid(Npad / 16), lblk(512);

  for (int l = 0; l < L; l++) {
    bool last = (l == L - 1);
    layer16<<<lgrid, lblk, 0, stream>>>(
        (const _Float16*)ping[l & 1], deg_in, ell,
        Whi + (size_t)l * 16384, Wlo + (size_t)l * 16384,
        bs + (size_t)l * D, deg_out,
        last ? nullptr : (__half*)ping[(l + 1) & 1],
        last ? outf : nullptr, N);
  }
}